// Round 1
// baseline (12.335 us; speedup 1.0000x reference)
//

#include <hip/hip_runtime.h>
#include <math.h>

// Problem constants from setup_inputs(): pred [N,T,C] f32, target [N,S] i32.
#define N_SAMPLES 128
#define T_DIM 256
#define C_DIM 2048
#define S_DIM 64
#define LOSS_WEIGHT 1.0f

// total = sum_i( valid_i ? -pred[i,0,target[i,0]] * W : 0 ) / N
// valid_i = all(target[i,:] != -1) && !isnan(loss_i); base term is exactly 0.
__global__ void __launch_bounds__(128)
mapping_ctc_loss_kernel(const float* __restrict__ pred,
                        const int* __restrict__ target,
                        float* __restrict__ out) {
    const int i = threadIdx.x;  // one thread per sample, blockDim.x == 128 == N
    float contrib = 0.0f;
    if (i < N_SAMPLES) {
        const int* trow = target + (size_t)i * S_DIM;
        // validity: original targets == -1 mark skipped samples
        bool valid = true;
        #pragma unroll 8
        for (int s = 0; s < S_DIM; ++s) {
            valid = valid && (trow[s] + 1 != 0);
        }
        const int t0 = trow[0];
        const float loss = -pred[(size_t)i * T_DIM * C_DIM + (size_t)t0];
        if (isnan(loss)) valid = false;
        if (valid) contrib = loss * LOSS_WEIGHT;
    }

    // reduce across the wave (64 lanes)
    #pragma unroll
    for (int off = 32; off > 0; off >>= 1) {
        contrib += __shfl_down(contrib, off, 64);
    }

    // combine the two waves
    __shared__ float wsum[2];
    const int wave = threadIdx.x >> 6;
    const int lane = threadIdx.x & 63;
    if (lane == 0) wsum[wave] = contrib;
    __syncthreads();
    if (threadIdx.x == 0) {
        out[0] = (wsum[0] + wsum[1]) * (1.0f / (float)N_SAMPLES);
    }
}

extern "C" void kernel_launch(void* const* d_in, const int* in_sizes, int n_in,
                              void* d_out, int out_size, void* d_ws, size_t ws_size,
                              hipStream_t stream) {
    const float* pred  = (const float*)d_in[0];  // [N, T, C] f32
    const int* target  = (const int*)d_in[1];    // [N, S] i32
    float* out = (float*)d_out;                  // scalar f32

    mapping_ctc_loss_kernel<<<1, 128, 0, stream>>>(pred, target, out);
}

// Round 2
// 9.656 us; speedup vs baseline: 1.2774x; 1.2774x over previous
//

#include <hip/hip_runtime.h>
#include <math.h>

// Problem constants from setup_inputs(): pred [N,T,C] f32, target [N,S] i32.
#define N_SAMPLES 128
#define T_DIM 256
#define C_DIM 2048
#define S_DIM 64
#define LOSS_WEIGHT 1.0f

// total = sum_i( valid_i ? -pred[i,0,target[i,0]] * W : 0 ) / N
// valid_i = all(target[i,:] != -1) && !isnan(loss_i); base term is exactly 0.
//
// Single tiny dispatch; optimize for latency:
//  - issue the dependent target[i*S] -> pred gather chain FIRST (HBM latency
//    overlaps the validity scan)
//  - validity scan int4-vectorized + coalesced across 1024 threads (16 waves)
//  - benign-race LDS invalid flags (only 1s are written)
__global__ void __launch_bounds__(1024)
mapping_ctc_loss_kernel(const float* __restrict__ pred,
                        const int* __restrict__ target,
                        float* __restrict__ out) {
    const int tid = threadIdx.x;

    __shared__ int s_invalid[N_SAMPLES];
    __shared__ float s_wsum[2];

    // Phase 0: per-sample gather chain, issued first so the latency hides
    // under the validity scan below.
    float loss = 0.0f;
    if (tid < N_SAMPLES) {
        const int t0 = target[tid * S_DIM];
        loss = -pred[(size_t)tid * (T_DIM * C_DIM) + (size_t)t0];
        s_invalid[tid] = 0;
    }
    __syncthreads();

    // Phase 1: validity scan. 128*64 ints = 2048 int4; 1024 threads x 2 int4,
    // fully coalesced. int4 index -> sample = idx >> 4.
    const int4* tv = (const int4*)target;
    #pragma unroll
    for (int k = 0; k < 2; ++k) {
        const int idx = tid + k * 1024;
        const int4 v = tv[idx];
        if (v.x == -1 || v.y == -1 || v.z == -1 || v.w == -1) {
            s_invalid[idx >> 4] = 1;  // benign race: only 1s written
        }
    }
    __syncthreads();

    // Phase 2: reduce over the first 2 waves (threads 0..127), one per sample.
    float contrib = 0.0f;
    if (tid < N_SAMPLES) {
        const bool valid = (s_invalid[tid] == 0) && !isnan(loss);
        contrib = valid ? loss * LOSS_WEIGHT : 0.0f;
    }
    if (tid < 128) {
        #pragma unroll
        for (int off = 32; off > 0; off >>= 1) {
            contrib += __shfl_down(contrib, off, 64);
        }
        if ((tid & 63) == 0) s_wsum[tid >> 6] = contrib;
    }
    __syncthreads();
    if (tid == 0) {
        out[0] = (s_wsum[0] + s_wsum[1]) * (1.0f / (float)N_SAMPLES);
    }
}

extern "C" void kernel_launch(void* const* d_in, const int* in_sizes, int n_in,
                              void* d_out, int out_size, void* d_ws, size_t ws_size,
                              hipStream_t stream) {
    const float* pred  = (const float*)d_in[0];  // [N, T, C] f32
    const int* target  = (const int*)d_in[1];    // [N, S] i32
    float* out = (float*)d_out;                  // scalar f32

    mapping_ctc_loss_kernel<<<1, 1024, 0, stream>>>(pred, target, out);
}